// Round 3
// baseline (634.448 us; speedup 1.0000x reference)
//
#include <hip/hip_runtime.h>

typedef unsigned short ushort_t;
typedef unsigned int u32;
typedef __attribute__((ext_vector_type(8))) short bf16x8;
typedef __attribute__((ext_vector_type(4))) float f32x4;

#define B_ 4
#define S_ 2048
#define D_ 2048
#define H_ 16
#define HD_ 128

__device__ __forceinline__ ushort_t f2bf(float f) {
  u32 x = __builtin_bit_cast(u32, f);
  x += 0x7fffu + ((x >> 16) & 1u);
  return (ushort_t)(x >> 16);
}
__device__ __forceinline__ float bf2f(ushort_t u) {
  u32 x = ((u32)u) << 16;
  return __builtin_bit_cast(float, x);
}

#define GLL16(srcp, ldsp)                                            \
  __builtin_amdgcn_global_load_lds(                                  \
      (const __attribute__((address_space(1))) u32*)(srcp),          \
      (__attribute__((address_space(3))) u32*)(ldsp), 16, 0, 0)

// ---------------- elementwise f32 -> bf16 convert ----------------
struct __align__(8) us4 { ushort_t x, y, z, w; };

__global__ void k_cvt_bf16(const float* __restrict__ in, ushort_t* __restrict__ out, int n) {
  int i = (blockIdx.x * 256 + threadIdx.x) * 4;
  if (i >= n) return;
  float4 v = *(const float4*)(in + i);
  us4 o;
  o.x = f2bf(v.x); o.y = f2bf(v.y); o.z = f2bf(v.z); o.w = f2bf(v.w);
  *(us4*)(out + i) = o;
}

// ---------------- f32 [R][C] -> bf16 [C][R] transpose ----------------
__global__ void k_transpose_bf16(const float* __restrict__ in, ushort_t* __restrict__ out,
                                 int R, int C) {
  __shared__ float ld[32][33];
  int c0 = blockIdx.x * 32, r0 = blockIdx.y * 32;
  int tc = threadIdx.x & 31, tr = threadIdx.x >> 5;  // tr 0..7
#pragma unroll
  for (int i = 0; i < 4; ++i) {
    int r = tr + i * 8;
    ld[r][tc] = in[(size_t)(r0 + r) * C + c0 + tc];
  }
  __syncthreads();
#pragma unroll
  for (int i = 0; i < 4; ++i) {
    int r = tr + i * 8;
    out[(size_t)(c0 + r) * R + r0 + tc] = f2bf(ld[tc][r]);
  }
}

// ---------------- RoPE cos/sin tables: [S][64] each ----------------
__global__ void k_rope_tables(float* __restrict__ cost, float* __restrict__ sint) {
  int i = blockIdx.x * 256 + threadIdx.x;  // < S_*64
  int s = i >> 6, j = i & 63;
  double th = pow(10000.0, -(double)j / 64.0);
  double a = (double)s * th;
  cost[i] = (float)cos(a);
  sint[i] = (float)sin(a);
}

// ---------------- bf16 GEMM 256x256 tile, BK=32, 3-ring LDS, counted vmcnt ----
// C[M][N] = A[M][K] * Bt[N][K]^T (+bias if FINAL)
template <int FINAL>
__global__ __launch_bounds__(512, 2) void k_gemm256(const ushort_t* __restrict__ A,
                                                    const ushort_t* __restrict__ Bt,
                                                    void* __restrict__ Cout,
                                                    const float* __restrict__ bias,
                                                    int M, int N, int K) {
  __shared__ __attribute__((aligned(16))) ushort_t As[3][256 * 32];  // 48KB
  __shared__ __attribute__((aligned(16))) ushort_t Bs[3][256 * 32];  // 48KB
  const int tid = threadIdx.x;
  const int w = tid >> 6, l = tid & 63;
  const int lr = l & 15, lg = l >> 4;
  const int wrr = w >> 2, wcc = w & 3;  // 2 x 4 wave grid; per-wave 128x64 out

  // XCD-aware block swizzle (grid % 8 == 0 by construction)
  const int nbn = N >> 8;
  const int cpx = gridDim.x >> 3;
  const int bid = blockIdx.x;
  const int swzid = (bid & 7) * cpx + (bid >> 3);
  const size_t m0 = (size_t)(swzid / nbn) * 256;
  const size_t n0 = (size_t)(swzid % nbn) * 256;

  const size_t Kp = (size_t)K * 2;  // row pitch bytes
  const char* Ab = (const char*)A + (m0) * Kp;
  const char* Bb = (const char*)Bt + (n0) * Kp;

  // staging chunks: c = tid, tid+512 ; row = c>>2, slot = c&3
  const int row0 = tid >> 2, slot0 = tid & 3;
  const int row1 = row0 + 128;
  const int xa0 = ((slot0 ^ ((row0 >> 1) & 3)) << 4);
  const int xa1 = ((slot0 ^ ((row1 >> 1) & 3)) << 4);

#define STAGE_A(t, bb)                                                    \
  {                                                                       \
    GLL16(Ab + (size_t)row0 * Kp + (size_t)(t) * 64 + xa0,                \
          (char*)As[bb] + (size_t)tid * 16);                              \
    GLL16(Ab + (size_t)row1 * Kp + (size_t)(t) * 64 + xa1,                \
          (char*)As[bb] + (size_t)(tid + 512) * 16);                      \
  }
#define STAGE_B(t, bb)                                                    \
  {                                                                       \
    GLL16(Bb + (size_t)row0 * Kp + (size_t)(t) * 64 + xa0,                \
          (char*)Bs[bb] + (size_t)tid * 16);                              \
    GLL16(Bb + (size_t)row1 * Kp + (size_t)(t) * 64 + xa1,                \
          (char*)Bs[bb] + (size_t)(tid + 512) * 16);                      \
  }

  // fragment read byte offsets (T2 swizzle: slot ^= (row>>1)&3 == (lr>>1)&3)
  const int swz2 = (lr >> 1) & 3;
  int aoff[8], boff[4];
#pragma unroll
  for (int m = 0; m < 8; ++m)
    aoff[m] = (wrr * 128 + m * 16 + lr) * 64 + ((lg ^ swz2) << 4);
#pragma unroll
  for (int n = 0; n < 4; ++n)
    boff[n] = (wcc * 64 + n * 16 + lr) * 64 + ((lg ^ swz2) << 4);

  f32x4 acc[8][4] = {};
  const int NT = K >> 5;

  STAGE_A(0, 0); STAGE_B(0, 0);
  STAGE_A(1, 1); STAGE_B(1, 1);
  asm volatile("s_waitcnt vmcnt(4)");
  __builtin_amdgcn_sched_barrier(0);
  __builtin_amdgcn_s_barrier();

  int bi = 0;
  for (int t = 0; t < NT; ++t) {
    int b2 = bi + 2; if (b2 >= 3) b2 -= 3;
    const char* Ac = (const char*)As[bi];
    const char* Bc = (const char*)Bs[bi];
    // ---- phase 1: quadrant m0..3 ----
    if (t + 2 < NT) STAGE_A(t + 2, b2);
    bf16x8 af0[4], bfr[4];
#pragma unroll
    for (int m = 0; m < 4; ++m) af0[m] = *(const bf16x8*)(Ac + aoff[m]);
#pragma unroll
    for (int n = 0; n < 4; ++n) bfr[n] = *(const bf16x8*)(Bc + boff[n]);
    asm volatile("s_waitcnt lgkmcnt(0)");
    __builtin_amdgcn_sched_barrier(0);
    __builtin_amdgcn_s_setprio(1);
#pragma unroll
    for (int m = 0; m < 4; ++m)
#pragma unroll
      for (int n = 0; n < 4; ++n)
        acc[m][n] = __builtin_amdgcn_mfma_f32_16x16x32_bf16(af0[m], bfr[n], acc[m][n], 0, 0, 0);
    __builtin_amdgcn_s_setprio(0);
    __builtin_amdgcn_s_barrier();
    // ---- phase 2: quadrant m4..7 ----
    if (t + 2 < NT) STAGE_B(t + 2, b2);
    bf16x8 af1[4];
#pragma unroll
    for (int m = 0; m < 4; ++m) af1[m] = *(const bf16x8*)(Ac + aoff[m + 4]);
    asm volatile("s_waitcnt lgkmcnt(0)");
    __builtin_amdgcn_sched_barrier(0);
    __builtin_amdgcn_s_setprio(1);
#pragma unroll
    for (int m = 0; m < 4; ++m)
#pragma unroll
      for (int n = 0; n < 4; ++n)
        acc[m + 4][n] = __builtin_amdgcn_mfma_f32_16x16x32_bf16(af1[m], bfr[n], acc[m + 4][n], 0, 0, 0);
    __builtin_amdgcn_s_setprio(0);
    // ---- end of tile: counted vmcnt (T4), raw barrier ----
    if (t + 1 < NT) {
      if (t + 2 < NT) asm volatile("s_waitcnt vmcnt(4)");
      else            asm volatile("s_waitcnt vmcnt(0)");
      __builtin_amdgcn_sched_barrier(0);
    }
    __builtin_amdgcn_s_barrier();
    bi = bi + 1; if (bi >= 3) bi = 0;
  }

  // ---- epilogue ----
#pragma unroll
  for (int n = 0; n < 4; ++n) {
    const size_t col = n0 + wcc * 64 + n * 16 + lr;
    float bia = FINAL ? bias[col] : 0.f;
#pragma unroll
    for (int m = 0; m < 8; ++m) {
#pragma unroll
      for (int j = 0; j < 4; ++j) {
        const size_t row = m0 + wrr * 128 + m * 16 + lg * 4 + j;
        if (FINAL) ((float*)Cout)[row * N + col] = acc[m][n][j] + bia;
        else       ((ushort_t*)Cout)[row * N + col] = f2bf(acc[m][n][j]);
      }
    }
  }
#undef STAGE_A
#undef STAGE_B
}

// ---------------- split QKV slice; RoPE for Q/K; transpose for V ----------------
__global__ void k_split_rope(const ushort_t* __restrict__ tmp, ushort_t* __restrict__ dst,
                             const float* __restrict__ cost, const float* __restrict__ sint,
                             int mode) {
  int s0 = blockIdx.x * 32;
  int h = blockIdx.y;
  int b = blockIdx.z;
  int bh = b * H_ + h;
  if (mode < 2) {
#pragma unroll
    for (int i = 0; i < 16; ++i) {
      int e = i * 256 + threadIdx.x;
      int sr = e >> 7, d = e & 127;
      int s = s0 + sr;
      size_t base = (size_t)(b * S_ + s) * D_ + h * HD_;
      float v = bf2f(tmp[base + d]);
      int j = d & 63;
      float cth = cost[s * 64 + j], sth = sint[s * 64 + j];
      int pd = (d < 64) ? d + 64 : d - 64;
      float v2 = bf2f(tmp[base + pd]);
      float r = (d < 64) ? v * cth - v2 * sth : v * cth + v2 * sth;
      dst[((size_t)bh * S_ + s) * HD_ + d] = f2bf(r);
    }
  } else {
    __shared__ ushort_t ld[32][132];
#pragma unroll
    for (int i = 0; i < 16; ++i) {
      int e = i * 256 + threadIdx.x;
      int sr = e >> 7, d = e & 127;
      ld[sr][d] = tmp[(size_t)(b * S_ + s0 + sr) * D_ + h * HD_ + d];
    }
    __syncthreads();
#pragma unroll
    for (int i = 0; i < 16; ++i) {
      int e = i * 256 + threadIdx.x;
      int d = e >> 5, sr = e & 31;
      dst[((size_t)bh * HD_ + d) * S_ + s0 + sr] = ld[sr][d];
    }
  }
}

// ---------------- causal flash attention v3 ----------------
// 512 threads / 8 waves, 32 q rows/wave (QBLK=256), KVBLK=64 double-buffered
// LDS with counted vmcnt + raw barriers; exp2-domain softmax + defer-max.
__global__ __launch_bounds__(512, 2) void k_attn3(const ushort_t* __restrict__ Q,
                                                  const ushort_t* __restrict__ K,
                                                  const ushort_t* __restrict__ Vt,
                                                  ushort_t* __restrict__ O) {
  __shared__ __attribute__((aligned(16))) ushort_t Ks[2][64 * 128];   // 32KB
  __shared__ __attribute__((aligned(16))) ushort_t Vs[2][128 * 64];   // 32KB
  __shared__ __attribute__((aligned(16))) ushort_t Pl[16][16 * 72];   // 36KB

  // block remap: XCD gets 8 contiguous bh (K/V L2 reuse); longest qt first
  const int id = blockIdx.x;                 // 0..511
  const int work = (id & 7) * 64 + (id >> 3);
  const int bh = work >> 3;
  const int qt = 7 - (work & 7);
  const int b = bh >> 4, h = bh & 15;

  const int tid = threadIdx.x;
  const int w = tid >> 6, l = tid & 63;
  const int lr = l & 15, lg = l >> 4;
  const int qb = qt * 256 + w * 32;

  const ushort_t* Qp = Q + (size_t)bh * S_ * HD_;
  const char* Kpb = (const char*)(K + (size_t)bh * S_ * HD_);
  const char* Vpb = (const char*)(Vt + (size_t)bh * HD_ * S_);
  const float kSc = 0.08838834764831845f * 1.4426950408889634f;  // scale * log2(e)

  // staging chunk decode (source pre-swizzled; LDS dest linear; rule #21)
  const int c1 = tid + 512;
  const int kr0 = tid >> 4, ks0 = (((tid & 15) ^ (kr0 & 15)) << 4);
  const int kr1 = c1 >> 4,  ks1 = (((c1 & 15) ^ (kr1 & 15)) << 4);
  const int vr0 = tid >> 3, vs0 = (((tid & 7) ^ (vr0 & 7)) << 4);
  const int vr1 = c1 >> 3,  vs1 = (((c1 & 7) ^ (vr1 & 7)) << 4);

#define STAGE_KV(bufi, kb_)                                                     \
  {                                                                             \
    GLL16(Kpb + (size_t)((kb_) + kr0) * 256 + ks0, (char*)Ks[bufi] + (size_t)tid * 16); \
    GLL16(Kpb + (size_t)((kb_) + kr1) * 256 + ks1, (char*)Ks[bufi] + (size_t)c1 * 16);  \
    GLL16(Vpb + (size_t)vr0 * (S_ * 2) + (size_t)(kb_) * 2 + vs0,               \
          (char*)Vs[bufi] + (size_t)tid * 16);                                  \
    GLL16(Vpb + (size_t)vr1 * (S_ * 2) + (size_t)(kb_) * 2 + vs1,               \
          (char*)Vs[bufi] + (size_t)c1 * 16);                                   \
  }

  // Q fragments (2 x 16 rows per wave)
  bf16x8 qf[2][4];
#pragma unroll
  for (int f = 0; f < 2; ++f)
#pragma unroll
    for (int dw = 0; dw < 4; ++dw)
      qf[f][dw] = *(const bf16x8*)(Qp + (size_t)(qb + f * 16 + lr) * HD_ + dw * 32 + lg * 8);

  f32x4 oacc[2][8] = {};
  float mr[2] = {-1e30f, -1e30f};
  float lsum[2] = {0.f, 0.f};
  const int nkt = 4 * qt + 4;

  STAGE_KV(0, 0);
  for (int kt = 0; kt < nkt; ++kt) {
    const int kb = kt * 64;
    const int cur = kt & 1;
    if (kt + 1 < nkt) {
      STAGE_KV(cur ^ 1, kb + 64);
      asm volatile("s_waitcnt vmcnt(4)");
    } else {
      asm volatile("s_waitcnt vmcnt(0)");
    }
    __builtin_amdgcn_sched_barrier(0);
    __builtin_amdgcn_s_barrier();

    if (kb <= qb + 31) {
      const char* Kc = (const char*)Ks[cur];
      const char* Vc = (const char*)Vs[cur];
      // ---- QK^T (swapped) ----
      f32x4 st[2][4];
      __builtin_amdgcn_s_setprio(1);
#pragma unroll
      for (int t = 0; t < 4; ++t) {
        bf16x8 kf[4];
#pragma unroll
        for (int dw = 0; dw < 4; ++dw)
          kf[dw] = *(const bf16x8*)(Kc + (t * 16 + lr) * 256 + (((dw * 4 + lg) ^ lr) << 4));
        f32x4 a0 = {}, a1 = {};
#pragma unroll
        for (int dw = 0; dw < 4; ++dw) {
          a0 = __builtin_amdgcn_mfma_f32_16x16x32_bf16(kf[dw], qf[0][dw], a0, 0, 0, 0);
          a1 = __builtin_amdgcn_mfma_f32_16x16x32_bf16(kf[dw], qf[1][dw], a1, 0, 0, 0);
        }
        st[0][t] = a0;
        st[1][t] = a1;
      }
      __builtin_amdgcn_s_setprio(0);

      // ---- online softmax (exp2 domain, defer-max) ----
#pragma unroll
      for (int f = 0; f < 2; ++f) {
        const int qg = qb + f * 16 + lr;
        float tmax = -1e30f;
#pragma unroll
        for (int t = 0; t < 4; ++t) {
#pragma unroll
          for (int j = 0; j < 4; ++j) {
            int kg = kb + t * 16 + lg * 4 + j;
            float s = st[f][t][j] * kSc;
            s = (kg > qg) ? -1e30f : s;
            st[f][t][j] = s;
            tmax = fmaxf(tmax, s);
          }
        }
        tmax = fmaxf(tmax, __shfl_xor(tmax, 16, 64));
        tmax = fmaxf(tmax, __shfl_xor(tmax, 32, 64));
        // defer-max (T13): skip rescale when no row grew past m+8
        if (!__all(tmax <= mr[f] + 8.f)) {
          float mnew = fmaxf(mr[f], tmax);
          float alpha = exp2f(mr[f] - mnew);
          mr[f] = mnew;
          lsum[f] *= alpha;
          float a0 = __shfl(alpha, lg * 4 + 0, 64);
          float a1 = __shfl(alpha, lg * 4 + 1, 64);
          float a2 = __shfl(alpha, lg * 4 + 2, 64);
          float a3 = __shfl(alpha, lg * 4 + 3, 64);
#pragma unroll
          for (int dt = 0; dt < 8; ++dt) {
            oacc[f][dt][0] *= a0;
            oacc[f][dt][1] *= a1;
            oacc[f][dt][2] *= a2;
            oacc[f][dt][3] *= a3;
          }
        }
        float psum = 0.f;
        ushort_t* Pw = (ushort_t*)Pl[w * 2 + f];
#pragma unroll
        for (int t = 0; t < 4; ++t) {
          float p0 = exp2f(st[f][t][0] - mr[f]);
          float p1 = exp2f(st[f][t][1] - mr[f]);
          float p2 = exp2f(st[f][t][2] - mr[f]);
          float p3 = exp2f(st[f][t][3] - mr[f]);
          psum += (p0 + p1) + (p2 + p3);
          *(u32*)&Pw[lr * 72 + t * 16 + lg * 4] = (u32)f2bf(p0) | ((u32)f2bf(p1) << 16);
          *(u32*)&Pw[lr * 72 + t * 16 + lg * 4 + 2] = (u32)f2bf(p2) | ((u32)f2bf(p3) << 16);
        }
        psum += __shfl_xor(psum, 16, 64);
        psum += __shfl_xor(psum, 32, 64);
        lsum[f] += psum;
      }

      // ---- PV ----
      __builtin_amdgcn_s_setprio(1);
#pragma unroll
      for (int kw = 0; kw < 2; ++kw) {
        bf16x8 pa0 = *(const bf16x8*)&Pl[w * 2 + 0][lr * 72 + kw * 32 + lg * 8];
        bf16x8 pa1 = *(const bf16x8*)&Pl[w * 2 + 1][lr * 72 + kw * 32 + lg * 8];
#pragma unroll
        for (int dt = 0; dt < 8; ++dt) {
          bf16x8 vf = *(const bf16x8*)(Vc + (dt * 16 + lr) * 128 + (((kw * 4 + lg) ^ (lr & 7)) << 4));
          oacc[0][dt] = __builtin_amdgcn_mfma_f32_16x16x32_bf16(pa0, vf, oacc[0][dt], 0, 0, 0);
          oacc[1][dt] = __builtin_amdgcn_mfma_f32_16x16x32_bf16(pa1, vf, oacc[1][dt], 0, 0, 0);
        }
      }
      __builtin_amdgcn_s_setprio(0);
    }
    __builtin_amdgcn_s_barrier();
  }

  // ---- epilogue ----
#pragma unroll
  for (int f = 0; f < 2; ++f) {
    float l0 = __shfl(lsum[f], lg * 4 + 0, 64);
    float l1 = __shfl(lsum[f], lg * 4 + 1, 64);
    float l2 = __shfl(lsum[f], lg * 4 + 2, 64);
    float l3 = __shfl(lsum[f], lg * 4 + 3, 64);
    float i0 = 1.f / l0, i1 = 1.f / l1, i2 = 1.f / l2, i3 = 1.f / l3;
    ushort_t* Op = O + (size_t)(b * S_ + qb + f * 16) * D_ + h * HD_;
#pragma unroll
    for (int dt = 0; dt < 8; ++dt) {
      Op[(size_t)(lg * 4 + 0) * D_ + dt * 16 + lr] = f2bf(oacc[f][dt][0] * i0);
      Op[(size_t)(lg * 4 + 1) * D_ + dt * 16 + lr] = f2bf(oacc[f][dt][1] * i1);
      Op[(size_t)(lg * 4 + 2) * D_ + dt * 16 + lr] = f2bf(oacc[f][dt][2] * i2);
      Op[(size_t)(lg * 4 + 3) * D_ + dt * 16 + lr] = f2bf(oacc[f][dt][3] * i3);
    }
  }
#undef STAGE_KV
}

// ---------------- launch ----------------
extern "C" void kernel_launch(void* const* d_in, const int* in_sizes, int n_in,
                              void* d_out, int out_size, void* d_ws, size_t ws_size,
                              hipStream_t stream) {
  const float* x = (const float*)d_in[0];
  const float* Wqkv = (const float*)d_in[1];
  const float* Wout = (const float*)d_in[2];
  const float* bout = (const float*)d_in[3];
  char* ws = (char*)d_ws;

  ushort_t* xb = (ushort_t*)(ws + 0);                  // [8192][2048] bf16 -> later O
  ushort_t* Wqt = (ushort_t*)(ws + 33554432ull);       // [6144][2048] bf16
  ushort_t* tmp = (ushort_t*)(ws + 58720256ull);       // [8192][2048] bf16 -> later Wout^T
  ushort_t* Qb = (ushort_t*)(ws + 92274688ull);        // [64][2048][128]
  ushort_t* Kb = (ushort_t*)(ws + 125829120ull);       // [64][2048][128]
  ushort_t* Vb = (ushort_t*)(ws + 159383552ull);       // [64][128][2048]
  float* cost = (float*)(ws + 192937984ull);           // [2048][64]
  float* sint = (float*)(ws + 193462272ull);           // [2048][64]

  const int M = B_ * S_;  // 8192

  k_cvt_bf16<<<dim3((M * D_) / 4 / 256), 256, 0, stream>>>(x, xb, M * D_);
  k_transpose_bf16<<<dim3(3 * D_ / 32, D_ / 32), 256, 0, stream>>>(Wqkv, Wqt, D_, 3 * D_);
  k_rope_tables<<<dim3(S_ * 64 / 256), 256, 0, stream>>>(cost, sint);

  for (int p = 0; p < 3; ++p) {
    k_gemm256<0><<<dim3((M / 256) * (D_ / 256)), 512, 0, stream>>>(
        xb, Wqt + (size_t)p * D_ * D_, tmp, nullptr, M, D_, D_);
    ushort_t* dst = (p == 0) ? Qb : (p == 1) ? Kb : Vb;
    k_split_rope<<<dim3(S_ / 32, H_, B_), 256, 0, stream>>>(tmp, dst, cost, sint, p);
  }

  k_attn3<<<dim3((S_ / 256) * B_ * H_), 512, 0, stream>>>(Qb, Kb, Vb, xb /* reuse as O */);

  k_transpose_bf16<<<dim3(D_ / 32, D_ / 32), 256, 0, stream>>>(Wout, tmp, D_, D_);
  k_gemm256<1><<<dim3((M / 256) * (D_ / 256)), 512, 0, stream>>>(
      xb, tmp, d_out, bout, M, D_, D_);
}

// Round 4
// 554.408 us; speedup vs baseline: 1.1444x; 1.1444x over previous
//
#include <hip/hip_runtime.h>

typedef unsigned short ushort_t;
typedef unsigned int u32;
typedef __attribute__((ext_vector_type(8))) short bf16x8;
typedef __attribute__((ext_vector_type(8))) unsigned short u16x8;
typedef __attribute__((ext_vector_type(4))) float f32x4;

#define B_ 4
#define S_ 2048
#define D_ 2048
#define H_ 16
#define HD_ 128

__device__ __forceinline__ ushort_t f2bf(float f) {
  u32 x = __builtin_bit_cast(u32, f);
  x += 0x7fffu + ((x >> 16) & 1u);
  return (ushort_t)(x >> 16);
}
__device__ __forceinline__ float bf2f(ushort_t u) {
  u32 x = ((u32)u) << 16;
  return __builtin_bit_cast(float, x);
}

#define GLL16(srcp, ldsp)                                            \
  __builtin_amdgcn_global_load_lds(                                  \
      (const __attribute__((address_space(1))) u32*)(srcp),          \
      (__attribute__((address_space(3))) u32*)(ldsp), 16, 0, 0)

// ---------------- elementwise f32 -> bf16 convert ----------------
struct __align__(8) us4 { ushort_t x, y, z, w; };

__global__ void k_cvt_bf16(const float* __restrict__ in, ushort_t* __restrict__ out, int n) {
  int i = (blockIdx.x * 256 + threadIdx.x) * 4;
  if (i >= n) return;
  float4 v = *(const float4*)(in + i);
  us4 o;
  o.x = f2bf(v.x); o.y = f2bf(v.y); o.z = f2bf(v.z); o.w = f2bf(v.w);
  *(us4*)(out + i) = o;
}

// ---------------- f32 [R][C] -> bf16 [C][R] transpose ----------------
__global__ void k_transpose_bf16(const float* __restrict__ in, ushort_t* __restrict__ out,
                                 int R, int C) {
  __shared__ float ld[32][33];
  int c0 = blockIdx.x * 32, r0 = blockIdx.y * 32;
  int tc = threadIdx.x & 31, tr = threadIdx.x >> 5;  // tr 0..7
#pragma unroll
  for (int i = 0; i < 4; ++i) {
    int r = tr + i * 8;
    ld[r][tc] = in[(size_t)(r0 + r) * C + c0 + tc];
  }
  __syncthreads();
#pragma unroll
  for (int i = 0; i < 4; ++i) {
    int r = tr + i * 8;
    out[(size_t)(c0 + r) * R + r0 + tc] = f2bf(ld[tc][r]);
  }
}

// ---------------- RoPE cos/sin tables: [S][64] each ----------------
__global__ void k_rope_tables(float* __restrict__ cost, float* __restrict__ sint) {
  int i = blockIdx.x * 256 + threadIdx.x;  // < S_*64
  int s = i >> 6, j = i & 63;
  double th = pow(10000.0, -(double)j / 64.0);
  double a = (double)s * th;
  cost[i] = (float)cos(a);
  sint[i] = (float)sin(a);
}

// ---------------- bf16 GEMM, m201-style: 256x256 tile, BK=64, 8-phase ----
// C[M][N] = A[M][K]*Bt[N][K]^T (+bias if FINAL). 512 thr / 8 waves.
// Wave w computes C rows 0..255 x cols [w*32, w*32+32) of the tile.
// Per K-tile: 4 phases, phase p = rows p*64..p*64+63 x K=64 (16 MFMA).
// LDS: A,B double-buffered 256x64 bf16 tiles (128KB). XOR swizzle ci^=(row&7).
// Stage order per tile t (for t+1): ph0:Alo ph1:Blo ph2:Bhi ph3:Ahi.
// Counted waits: end-ph1 vmcnt(4); end-ph3 vmcnt(4) (waves 0-3) / vmcnt(2) (4-7).
template <int FINAL>
__global__ __launch_bounds__(512) void k_gemm8p(const ushort_t* __restrict__ A,
                                                const ushort_t* __restrict__ Bt,
                                                void* __restrict__ Cout,
                                                const float* __restrict__ bias,
                                                int M, int N, int K) {
  __shared__ __attribute__((aligned(16))) ushort_t As[2][256 * 64];  // 64KB
  __shared__ __attribute__((aligned(16))) ushort_t Bs[2][256 * 64];  // 64KB
  const int tid = threadIdx.x;
  const int w = tid >> 6, l = tid & 63;
  const int lr = l & 15, lg = l >> 4;

  // bijective XCD swizzle (gridDim.x % 8 == 0)
  const int cpx = gridDim.x >> 3;
  const int bid = blockIdx.x;
  const int swzid = (bid & 7) * cpx + (bid >> 3);
  const int nbn = N >> 8;
  const size_t m0 = (size_t)(swzid / nbn) * 256;
  const size_t n0 = (size_t)(swzid % nbn) * 256;

  const size_t Kp = (size_t)K * 2;
  const char* Ab = (const char*)A + m0 * Kp;
  const char* Bb = (const char*)Bt + n0 * Kp;

  const int r0 = tid >> 3;                       // 0..63
  const int ci16 = (tid & 7) * 16;
  const int sw0 = (((tid & 7) ^ (r0 & 7)) << 4); // pre-swizzled source chunk

#define STG_HALF(gbase, hrow, ldsbase, tcol)                                   \
  {                                                                            \
    GLL16((gbase) + (size_t)((hrow) + r0) * Kp + (tcol) + sw0,                 \
          (char*)(ldsbase) + ((hrow) + r0) * 128 + ci16);                      \
    GLL16((gbase) + (size_t)((hrow) + r0 + 64) * Kp + (tcol) + sw0,            \
          (char*)(ldsbase) + ((hrow) + r0 + 64) * 128 + ci16);                 \
  }

  // fragment chunk offsets (read-side swizzle)
  const int cko0 = (((0 * 4 + lg) ^ (lr & 7)) << 4);
  const int cko1 = (((1 * 4 + lg) ^ (lr & 7)) << 4);

  f32x4 acc[16][2] = {};
  const int NT = K >> 6;  // 32

  // prologue: stage tile 0 (Alo, Blo, Bhi, Ahi)
  STG_HALF(Ab, 0, As[0], 0);
  STG_HALF(Bb, 0, Bs[0], 0);
  STG_HALF(Bb, 128, Bs[0], 0);
  STG_HALF(Ab, 128, As[0], 0);
  if (w < 4) asm volatile("s_waitcnt vmcnt(4)");
  else       asm volatile("s_waitcnt vmcnt(2)");
  __builtin_amdgcn_sched_barrier(0);
  __builtin_amdgcn_s_barrier();

  bf16x8 bq[2][2];  // wave's B frags (n, ks) — persist across phases
  for (int t = 0; t < NT; ++t) {
    const int buf = t & 1;
    const char* Ac = (const char*)As[buf];
    const char* Bc = (const char*)Bs[buf];
    const size_t tc1 = (size_t)(t + 1) * 128;  // next tile col bytes
    const bool more = (t + 1 < NT);
#pragma unroll
    for (int p = 0; p < 4; ++p) {
      // ---- stage one half-tile of t+1 ----
      if (more) {
        if (p == 0) STG_HALF(Ab, 0, As[buf ^ 1], tc1)
        else if (p == 1) STG_HALF(Bb, 0, Bs[buf ^ 1], tc1)
        else if (p == 2) STG_HALF(Bb, 128, Bs[buf ^ 1], tc1)
        else STG_HALF(Ab, 128, As[buf ^ 1], tc1)
      }
      // ---- ds reads for this phase ----
      bf16x8 af[4][2];
#pragma unroll
      for (int m = 0; m < 4; ++m) {
        const int row = p * 64 + m * 16 + lr;
        af[m][0] = *(const bf16x8*)(Ac + row * 128 + cko0);
        af[m][1] = *(const bf16x8*)(Ac + row * 128 + cko1);
      }
      if (p == 0) {
#pragma unroll
        for (int n = 0; n < 2; ++n) {
          const int row = w * 32 + n * 16 + lr;
          bq[n][0] = *(const bf16x8*)(Bc + row * 128 + cko0);
          bq[n][1] = *(const bf16x8*)(Bc + row * 128 + cko1);
        }
      }
      __builtin_amdgcn_s_barrier();
      asm volatile("s_waitcnt lgkmcnt(0)");
      __builtin_amdgcn_sched_barrier(0);
      __builtin_amdgcn_s_setprio(1);
#pragma unroll
      for (int m = 0; m < 4; ++m)
#pragma unroll
        for (int n = 0; n < 2; ++n) {
          acc[p * 4 + m][n] =
              __builtin_amdgcn_mfma_f32_16x16x32_bf16(af[m][0], bq[n][0], acc[p * 4 + m][n], 0, 0, 0);
          acc[p * 4 + m][n] =
              __builtin_amdgcn_mfma_f32_16x16x32_bf16(af[m][1], bq[n][1], acc[p * 4 + m][n], 0, 0, 0);
        }
      __builtin_amdgcn_s_setprio(0);
      // ---- end-of-phase counted waits ----
      if (p == 1) {
        if (more) asm volatile("s_waitcnt vmcnt(4)");
        else      asm volatile("s_waitcnt vmcnt(0)");
        __builtin_amdgcn_sched_barrier(0);
      } else if (p == 3 && more) {
        if (w < 4) asm volatile("s_waitcnt vmcnt(4)");
        else       asm volatile("s_waitcnt vmcnt(2)");
        __builtin_amdgcn_sched_barrier(0);
      }
      __builtin_amdgcn_s_barrier();
    }
  }

  // ---- epilogue ----
#pragma unroll
  for (int n = 0; n < 2; ++n) {
    const size_t col = n0 + w * 32 + n * 16 + lr;
    float bia = FINAL ? bias[col] : 0.f;
#pragma unroll
    for (int mq = 0; mq < 16; ++mq) {
#pragma unroll
      for (int j = 0; j < 4; ++j) {
        const size_t row = m0 + mq * 16 + lg * 4 + j;
        if (FINAL) ((float*)Cout)[row * N + col] = acc[mq][n][j] + bia;
        else       ((ushort_t*)Cout)[row * N + col] = f2bf(acc[mq][n][j]);
      }
    }
  }
#undef STG_HALF
}

// ---------------- split QKV slice; RoPE for Q/K; transpose for V ----------------
// mode 0: Q rope (pre-scaled by qscale) -> [B*H][S][HD]
// mode 1: K rope -> [B*H][S][HD]; mode 2: V -> [B*H][HD][S]
__global__ void k_split_rope(const ushort_t* __restrict__ tmp, ushort_t* __restrict__ dst,
                             const float* __restrict__ cost, const float* __restrict__ sint,
                             int mode, float qscale) {
  int s0 = blockIdx.x * 32;
  int h = blockIdx.y;
  int b = blockIdx.z;
  int bh = b * H_ + h;
  if (mode < 2) {
    const int t = threadIdx.x;
    const int sr = t >> 3, dj = (t & 7) * 8;
    const int s = s0 + sr;
    const size_t base = (size_t)(b * S_ + s) * D_ + h * HD_;
    u16x8 lo = *(const u16x8*)(tmp + base + dj);
    u16x8 hi = *(const u16x8*)(tmp + base + 64 + dj);
    const float* cs = cost + s * 64 + dj;
    const float* sn = sint + s * 64 + dj;
    u16x8 olo, ohi;
#pragma unroll
    for (int j = 0; j < 8; ++j) {
      float fl = bf2f(lo[j]), fh = bf2f(hi[j]);
      float c = cs[j], sv = sn[j];
      olo[j] = f2bf((fl * c - fh * sv) * qscale);
      ohi[j] = f2bf((fh * c + fl * sv) * qscale);
    }
    ushort_t* dp = dst + ((size_t)bh * S_ + s) * HD_;
    *(u16x8*)(dp + dj) = olo;
    *(u16x8*)(dp + 64 + dj) = ohi;
  } else {
    __shared__ ushort_t ld[32][132];
#pragma unroll
    for (int i = 0; i < 2; ++i) {
      int e = i * 256 + threadIdx.x;
      int sr = e >> 4, dj = (e & 15) * 8;
      *(u16x8*)&ld[sr][dj] = *(const u16x8*)(tmp + (size_t)(b * S_ + s0 + sr) * D_ + h * HD_ + dj);
    }
    __syncthreads();
#pragma unroll
    for (int i = 0; i < 16; ++i) {
      int e = i * 256 + threadIdx.x;
      int d = e >> 5, sr = e & 31;
      dst[((size_t)bh * HD_ + d) * S_ + s0 + sr] = ld[sr][d];
    }
  }
}

// ---------------- causal flash attention v4 ----------------
// Q,K: [B*H][S][HD] bf16 (Q pre-scaled by scale*log2e); Vt: [B*H][HD][S];
// O: [B][S][H*HD] bf16. 4 waves, 32 q/wave (QBLK=128), KVBLK=64.
// K double-buffered + V single-buffered LDS, counted vmcnt. exp2 softmax,
// defer-max, cvt_pk P-pack, maskless full tiles.
__global__ __launch_bounds__(256, 2) void k_attn4(const ushort_t* __restrict__ Q,
                                                  const ushort_t* __restrict__ K,
                                                  const ushort_t* __restrict__ Vt,
                                                  ushort_t* __restrict__ O) {
  __shared__ __attribute__((aligned(16))) ushort_t Ks[2][64 * 128];  // 32KB
  __shared__ __attribute__((aligned(16))) ushort_t Vs[128 * 64];     // 16KB
  __shared__ __attribute__((aligned(16))) ushort_t Pl[8][16 * 72];   // 18KB

  const int id = blockIdx.x;  // 0..1023
  const int work = (id & 7) * 128 + (id >> 3);
  const int bh = work >> 4;
  const int qt = 15 - (work & 15);
  const int b = bh >> 4, h = bh & 15;

  const int tid = threadIdx.x;
  const int w = tid >> 6, l = tid & 63;
  const int lr = l & 15, lg = l >> 4;
  const int qb = qt * 128 + w * 32;

  const ushort_t* Qp = Q + (size_t)bh * S_ * HD_;
  const char* Kpb = (const char*)(K + (size_t)bh * S_ * HD_);
  const char* Vpb = (const char*)(Vt + (size_t)bh * HD_ * S_);

  // staging decode (pre-swizzled source, linear LDS dest)
  int kr[4], ksz[4], vr[4], vsz[4];
#pragma unroll
  for (int r = 0; r < 4; ++r) {
    int c = r * 256 + tid;
    kr[r] = c >> 4;
    ksz[r] = (((c & 15) ^ (kr[r] & 15)) << 4);
    vr[r] = c >> 3;
    vsz[r] = (((c & 7) ^ (vr[r] & 7)) << 4);
  }

#define STAGE_K(kb_, bufi)                                                       \
  {                                                                              \
    _Pragma("unroll") for (int r = 0; r < 4; ++r)                                \
        GLL16(Kpb + (size_t)((kb_) + kr[r]) * 256 + ksz[r],                      \
              (char*)Ks[bufi] + (size_t)(r * 256 + tid) * 16);                   \
  }
#define STAGE_V(kb_)                                                             \
  {                                                                              \
    _Pragma("unroll") for (int r = 0; r < 4; ++r)                                \
        GLL16(Vpb + (size_t)vr[r] * (S_ * 2) + (size_t)(kb_) * 2 + vsz[r],       \
              (char*)Vs + (size_t)(r * 256 + tid) * 16);                         \
  }

  bf16x8 qf[2][4];
#pragma unroll
  for (int f = 0; f < 2; ++f)
#pragma unroll
    for (int dw = 0; dw < 4; ++dw)
      qf[f][dw] = *(const bf16x8*)(Qp + (size_t)(qb + f * 16 + lr) * HD_ + dw * 32 + lg * 8);

  f32x4 oacc[2][8] = {};
  float mr[2] = {-1e30f, -1e30f};
  float lsum[2] = {0.f, 0.f};
  const int nkt = 2 * qt + 2;

  STAGE_K(0, 0);
  for (int kt = 0; kt < nkt; ++kt) {
    const int kb = kt * 64;
    const int cur = kt & 1;
    const bool morek = (kt + 1 < nkt);
    if (morek) STAGE_K(kb + 64, cur ^ 1);
    STAGE_V(kb);
    if (morek) asm volatile("s_waitcnt vmcnt(8)");
    else       asm volatile("s_waitcnt vmcnt(4)");
    __builtin_amdgcn_sched_barrier(0);
    __builtin_amdgcn_s_barrier();  // K(t) ready

    const bool live = (kb <= qb + 31);
    f32x4 st[2][4];
    if (live) {
      const char* Kc = (const char*)Ks[cur];
      __builtin_amdgcn_s_setprio(1);
#pragma unroll
      for (int t = 0; t < 4; ++t) {
        bf16x8 kf[4];
#pragma unroll
        for (int dw = 0; dw < 4; ++dw)
          kf[dw] = *(const bf16x8*)(Kc + (t * 16 + lr) * 256 + (((dw * 4 + lg) ^ lr) << 4));
        f32x4 a0 = {}, a1 = {};
#pragma unroll
        for (int dw = 0; dw < 4; ++dw) {
          a0 = __builtin_amdgcn_mfma_f32_16x16x32_bf16(kf[dw], qf[0][dw], a0, 0, 0, 0);
          a1 = __builtin_amdgcn_mfma_f32_16x16x32_bf16(kf[dw], qf[1][dw], a1, 0, 0, 0);
        }
        st[0][t] = a0;
        st[1][t] = a1;
      }
      __builtin_amdgcn_s_setprio(0);

      // online softmax (log2 domain; Q pre-scaled)
#pragma unroll
      for (int f = 0; f < 2; ++f) {
        const int qg = qb + f * 16 + lr;
        const bool full = (kb + 63) <= (qb + f * 16);
        float tmax = -1e30f;
        if (full) {
#pragma unroll
          for (int t = 0; t < 4; ++t)
#pragma unroll
            for (int j = 0; j < 4; ++j) tmax = fmaxf(tmax, st[f][t][j]);
        } else {
#pragma unroll
          for (int t = 0; t < 4; ++t)
#pragma unroll
            for (int j = 0; j < 4; ++j) {
              int kg = kb + t * 16 + lg * 4 + j;
              float s = (kg > qg) ? -1e30f : st[f][t][j];
              st[f][t][j] = s;
              tmax = fmaxf(tmax, s);
            }
        }
        tmax = fmaxf(tmax, __shfl_xor(tmax, 16, 64));
        tmax = fmaxf(tmax, __shfl_xor(tmax, 32, 64));
        if (!__all(tmax <= mr[f] + 8.f)) {
          float mnew = fmaxf(mr[f], tmax);
          float alpha = exp2f(mr[f] - mnew);
          mr[f] = mnew;
          lsum[f] *= alpha;
          float a0 = __shfl(alpha, lg * 4 + 0, 64);
          float a1 = __shfl(alpha, lg * 4 + 1, 64);
          float a2 = __shfl(alpha, lg * 4 + 2, 64);
          float a3 = __shfl(alpha, lg * 4 + 3, 64);
#pragma unroll
          for (int dt = 0; dt < 8; ++dt) {
            oacc[f][dt][0] *= a0;
            oacc[f][dt][1] *= a1;
            oacc[f][dt][2] *= a2;
            oacc[f][dt][3] *= a3;
          }
        }
        float psum = 0.f;
        ushort_t* Pw = (ushort_t*)Pl[w * 2 + f];
#pragma unroll
        for (int t = 0; t < 4; ++t) {
          float p0 = exp2f(st[f][t][0] - mr[f]);
          float p1 = exp2f(st[f][t][1] - mr[f]);
          float p2 = exp2f(st[f][t][2] - mr[f]);
          float p3 = exp2f(st[f][t][3] - mr[f]);
          psum += (p0 + p1) + (p2 + p3);
          u32 pk0, pk1;
          asm("v_cvt_pk_bf16_f32 %0, %1, %2" : "=v"(pk0) : "v"(p0), "v"(p1));
          asm("v_cvt_pk_bf16_f32 %0, %1, %2" : "=v"(pk1) : "v"(p2), "v"(p3));
          *(u32*)&Pw[lr * 72 + t * 16 + lg * 4] = pk0;
          *(u32*)&Pw[lr * 72 + t * 16 + lg * 4 + 2] = pk1;
        }
        psum += __shfl_xor(psum, 16, 64);
        psum += __shfl_xor(psum, 32, 64);
        lsum[f] += psum;
      }
    }
    // V(t) ready (all waves must pass)
    if (morek) asm volatile("s_waitcnt vmcnt(4)");
    else       asm volatile("s_waitcnt vmcnt(0)");
    __builtin_amdgcn_sched_barrier(0);
    __builtin_amdgcn_s_barrier();

    if (live) {
      __builtin_amdgcn_s_setprio(1);
#pragma unroll
      for (int kw = 0; kw < 2; ++kw) {
        bf16x8 pa0 = *(const bf16x8*)&Pl[w * 2 + 0][lr * 72 + kw * 32 + lg * 8];
        bf16x8 pa1 = *(const bf16x8*)&Pl[w * 2 + 1][lr * 72 + kw * 32 + lg * 8];
#pragma unroll
        for (int dt = 0; dt < 8; ++dt) {
          bf16x8 vf = *(const bf16x8*)((const char*)Vs + (dt * 16 + lr) * 128 +
                                       (((kw * 4 + lg) ^ (lr & 7)) << 4));
          oacc[0][dt] = __builtin_amdgcn_mfma_f32_16x16x32_bf16(pa0, vf, oacc[0][dt], 0, 0, 0);
          oacc[1][dt] = __builtin_amdgcn_mfma_f32_16x16x32_bf16(pa1, vf, oacc[1][dt], 0, 0, 0);
        }
      }
      __builtin_amdgcn_s_setprio(0);
    }
    __builtin_amdgcn_s_barrier();  // end of tile (V reads done before restage)
  }

  // ---- epilogue ----
#pragma unroll
  for (int f = 0; f < 2; ++f) {
    float l0 = __shfl(lsum[f], lg * 4 + 0, 64);
    float l1 = __shfl(lsum[f], lg * 4 + 1, 64);
    float l2 = __shfl(lsum[f], lg * 4 + 2, 64);
    float l3 = __shfl(lsum[f], lg * 4 + 3, 64);
    float i0 = 1.f / l0, i1 = 1.f / l1, i2 = 1.f / l2, i3 = 1.f / l3;
    ushort_t* Op = O + (size_t)(b * S_ + qb + f * 16) * D_ + h * HD_;
#pragma unroll
    for (int dt = 0; dt < 8; ++dt) {
      Op[(size_t)(lg * 4 + 0) * D_ + dt * 16 + lr] = f2bf(oacc[f][dt][0] * i0);
      Op[(size_t)(lg * 4 + 1) * D_ + dt * 16 + lr] = f2bf(oacc[f][dt][1] * i1);
      Op[(size_t)(lg * 4 + 2) * D_ + dt * 16 + lr] = f2bf(oacc[f][dt][2] * i2);
      Op[(size_t)(lg * 4 + 3) * D_ + dt * 16 + lr] = f2bf(oacc[f][dt][3] * i3);
    }
  }
#undef STAGE_K
#undef STAGE_V
}

// ---------------- launch ----------------
extern "C" void kernel_launch(void* const* d_in, const int* in_sizes, int n_in,
                              void* d_out, int out_size, void* d_ws, size_t ws_size,
                              hipStream_t stream) {
  const float* x = (const float*)d_in[0];
  const float* Wqkv = (const float*)d_in[1];
  const float* Wout = (const float*)d_in[2];
  const float* bout = (const float*)d_in[3];
  char* ws = (char*)d_ws;

  ushort_t* xb = (ushort_t*)(ws + 0);                  // [8192][2048] bf16 -> later O
  ushort_t* Wqt = (ushort_t*)(ws + 33554432ull);       // [6144][2048] bf16
  ushort_t* tmp = (ushort_t*)(ws + 58720256ull);       // [8192][2048] bf16 -> later Wout^T
  ushort_t* Qb = (ushort_t*)(ws + 92274688ull);        // [64][2048][128]
  ushort_t* Kb = (ushort_t*)(ws + 125829120ull);       // [64][2048][128]
  ushort_t* Vb = (ushort_t*)(ws + 159383552ull);       // [64][128][2048]
  float* cost = (float*)(ws + 192937984ull);           // [2048][64]
  float* sint = (float*)(ws + 193462272ull);           // [2048][64]

  const int M = B_ * S_;  // 8192
  const float kSc = 0.08838834764831845f * 1.4426950408889634f;  // 1/sqrt(128)*log2e

  k_cvt_bf16<<<dim3((M * D_) / 4 / 256), 256, 0, stream>>>(x, xb, M * D_);
  k_transpose_bf16<<<dim3(3 * D_ / 32, D_ / 32), 256, 0, stream>>>(Wqkv, Wqt, D_, 3 * D_);
  k_rope_tables<<<dim3(S_ * 64 / 256), 256, 0, stream>>>(cost, sint);

  for (int p = 0; p < 3; ++p) {
    k_gemm8p<0><<<dim3((M / 256) * (D_ / 256)), 512, 0, stream>>>(
        xb, Wqt + (size_t)p * D_ * D_, tmp, nullptr, M, D_, D_);
    ushort_t* dst = (p == 0) ? Qb : (p == 1) ? Kb : Vb;
    k_split_rope<<<dim3(S_ / 32, H_, B_), 256, 0, stream>>>(
        tmp, dst, cost, sint, p, (p == 0) ? kSc : 1.0f);
  }

  k_attn4<<<dim3((S_ / 128) * B_ * H_), 256, 0, stream>>>(Qb, Kb, Vb, xb /* reuse as O */);

  k_transpose_bf16<<<dim3(D_ / 32, D_ / 32), 256, 0, stream>>>(Wout, tmp, D_, D_);
  k_gemm8p<1><<<dim3((M / 256) * (D_ / 256)), 512, 0, stream>>>(
      xb, tmp, d_out, bout, M, D_, D_);
}